// Round 9
// baseline (8309.911 us; speedup 1.0000x reference)
//
#include <hip/hip_runtime.h>
#include <hip/hip_bf16.h>

typedef __hip_bfloat16 bf16;
typedef __attribute__((ext_vector_type(8))) short short8;
typedef __attribute__((ext_vector_type(4))) short s16x4;
typedef __attribute__((ext_vector_type(2))) short s16x2;
typedef __attribute__((ext_vector_type(4))) float f32x4;

#define MFMA(a, b, c) __builtin_amdgcn_mfma_f32_16x16x32_bf16(a, b, c, 0, 0, 0)

__device__ __forceinline__ float to_f(bf16 x) { return __bfloat162float(x); }
__device__ __forceinline__ float b2f(short s) {
  bf16 h;
  *reinterpret_cast<short*>(&h) = s;
  return __bfloat162float(h);
}
__device__ __forceinline__ short f2b(float f) {
  bf16 h = __float2bfloat16(f);
  return *reinterpret_cast<short*>(&h);
}
__device__ __forceinline__ float ldp(const void* p, size_t i, bool f32) {
  return f32 ? ((const float*)p)[i] : to_f(((const bf16*)p)[i]);
}
__device__ __forceinline__ float fsig(float x) {
  return __builtin_amdgcn_rcpf(1.f + __expf(-x));
}
__device__ __forceinline__ float ftanh(float x) {
  float t = __expf(-2.f * fabsf(x));
  float r = (1.f - t) * __builtin_amdgcn_rcpf(1.f + t);
  return x < 0.f ? -r : r;
}

// dtype probe: f32 data read as u16 pairs shows implausible bf16 exponents.
__global__ void detect_kernel(const void* __restrict__ probe,
                              unsigned* __restrict__ flag) {
  __shared__ int sbad;
  if (threadIdx.x == 0) sbad = 0;
  __syncthreads();
  const unsigned short* u = (const unsigned short*)probe;
  int bad = 0;
  for (int i = threadIdx.x; i < 2048; i += 256) {
    unsigned short w = u[i];
    unsigned e = (w >> 7) & 0xFFu;
    bool plaus = (w == 0) || (w == 0x8000u) || (e >= 0x60u && e <= 0x7Eu);
    if (!plaus) bad++;
  }
  atomicAdd(&sbad, bad);
  __syncthreads();
  if (threadIdx.x == 0) *flag = (sbad > 100) ? 1u : 0u;
}

// ---- weight prep: params (f32|bf16) -> bf16 ws; optional transpose; ----
// ---- src has its own row stride (sstride) for column slicing. ----
#define MAXSEG 28
struct PrepArgs {
  int nseg;
  const void* src[MAXSEG];
  long long soff[MAXSEG];
  short* dst[MAXSEG];
  int scols[MAXSEG];
  int sstride[MAXSEG];
  int dstride[MAXSEG];
  int transp[MAXSEG];
  long long prefix[MAXSEG + 1];
};
__global__ void prep_kernel(PrepArgs a, const unsigned* __restrict__ dflag) {
  const bool isf32 = (*dflag != 0u);
  long long i = (long long)blockIdx.x * 256 + threadIdx.x;
  if (i >= a.prefix[a.nseg]) return;
  int s = 0;
  while (i >= a.prefix[s + 1]) s++;
  long long loc = i - a.prefix[s];
  long long r = loc / a.scols[s], c = loc % a.scols[s];
  float v = ldp(a.src[s], (size_t)(a.soff[s] + r * a.sstride[s] + c), isf32);
  long long idx =
      a.transp[s] ? (c * a.dstride[s] + r) : (r * a.dstride[s] + c);
  a.dst[s][idx] = f2b(v);
}

// ---- multi-job MFMA GEMM, 128x128 tile (proven round-8 kernel) ----
struct GJob {
  const bf16* A;
  const int* rowidx;
  const short* WT;
  const bf16* bias;
  float* Cf;
  bf16* Ch;
  int lda, wst, K, M, N, flags;  // flags: 1=gather, 4=tanh
};
struct GJobs {
  GJob j[2];
};

__global__ __launch_bounds__(256) void mj_gemm(GJobs args) {
  GJob jb = args.j[blockIdx.z];
  const int n0 = blockIdx.x * 128, m0 = blockIdx.y * 128;
  if (n0 >= jb.N || m0 >= jb.M) return;
  __shared__ short As[128][40];
  __shared__ short Bs[128][40];
  __shared__ int rows[128];
  const int tid = threadIdx.x, lane = tid & 63, wave = tid >> 6;
  const int srow = tid >> 1, skoff = (tid & 1) * 16;
  const int wr = (wave >> 1) * 64, wc = (wave & 1) * 64;
  if (jb.flags & 1) {
    if (tid < 128) rows[tid] = jb.rowidx[m0 + tid];
    __syncthreads();
  }
  const long long arow =
      (jb.flags & 1) ? (long long)rows[srow] : (long long)(m0 + srow);
  const short* abase = (const short*)jb.A + arow * jb.lda + skoff;
  const short* bbase = jb.WT + (long long)(n0 + srow) * jb.wst + skoff;
  f32x4 acc[4][4];
#pragma unroll
  for (int i = 0; i < 4; i++)
#pragma unroll
    for (int j = 0; j < 4; j++) acc[i][j] = 0.f;
  const int K = jb.K;
  short8 a0 = *(const short8*)(abase);
  short8 a1 = *(const short8*)(abase + 8);
  short8 b0 = *(const short8*)(bbase);
  short8 b1 = *(const short8*)(bbase + 8);
  for (int k0 = 0; k0 < K; k0 += 32) {
    __syncthreads();
    *(short8*)&As[srow][skoff] = a0;
    *(short8*)&As[srow][skoff + 8] = a1;
    *(short8*)&Bs[srow][skoff] = b0;
    *(short8*)&Bs[srow][skoff + 8] = b1;
    __syncthreads();
    int kn = (k0 + 32 < K) ? k0 + 32 : k0;
    a0 = *(const short8*)(abase + kn);
    a1 = *(const short8*)(abase + kn + 8);
    b0 = *(const short8*)(bbase + kn);
    b1 = *(const short8*)(bbase + kn + 8);
    short8 af[4], bfr[4];
#pragma unroll
    for (int i = 0; i < 4; i++)
      af[i] = *(short8*)&As[wr + i * 16 + (lane & 15)][(lane >> 4) * 8];
#pragma unroll
    for (int j = 0; j < 4; j++)
      bfr[j] = *(short8*)&Bs[wc + j * 16 + (lane & 15)][(lane >> 4) * 8];
#pragma unroll
    for (int i = 0; i < 4; i++)
#pragma unroll
      for (int j = 0; j < 4; j++)
        acc[i][j] = MFMA(af[i], bfr[j], acc[i][j]);
  }
  const int N = jb.N;
#pragma unroll
  for (int j = 0; j < 4; j++) {
    int col = n0 + wc + j * 16 + (lane & 15);
    float bv = jb.bias ? to_f(jb.bias[col]) : 0.f;
#pragma unroll
    for (int i = 0; i < 4; i++) {
#pragma unroll
      for (int r = 0; r < 4; r++) {
        int row = m0 + wr + i * 16 + (lane >> 4) * 4 + r;
        float v = acc[i][j][r] + bv;
        if (jb.flags & 4) v = ftanh(v);
        if (jb.Cf) jb.Cf[(long long)row * N + col] = v;
        if (jb.Ch) jb.Ch[(long long)row * N + col] = __float2bfloat16(v);
      }
    }
  }
}

// ---- persistent encoder: block = (32 batch rows, dir); 24 steps in-kernel.
// Per step: S = [x|h] @ [Wih;Whh]^T (K=576) + gh_n = h @ Whh[:,512:768]^T;
// cell in registers (h carry in VGPRs, f32); bse written per step.
__global__ __launch_bounds__(256, 1) void enc_persist(
    const bf16* __restrict__ embE, const int* __restrict__ src,
    const short* __restrict__ WsF, const short* __restrict__ WsB,
    const short* __restrict__ WhnF, const short* __restrict__ WhnB,
    const bf16* __restrict__ BihF, const bf16* __restrict__ BhhF,
    const bf16* __restrict__ BihB, const bf16* __restrict__ BhhB,
    bf16* __restrict__ bse, bf16* __restrict__ hbf) {
  const int dir = blockIdx.y;
  const int b0 = blockIdx.x * 32;
  const short* Ws = dir ? WsB : WsF;
  const short* Whn = dir ? WhnB : WhnF;
  const bf16* Bih = dir ? BihB : BihF;
  const bf16* Bhh = dir ? BhhB : BhhF;
  __shared__ short xh[32][584];  // [row][k]: x 0:320, h 320:576, pad
  __shared__ int idx[32];
  const int tid = threadIdx.x, lane = tid & 63, w = tid >> 6;
  const int l15 = lane & 15, q8 = (lane >> 4) * 8, qr = (lane >> 4) * 4;

  float hreg[2][4][4];  // persistent h: [m][j][r], row=m*16+qr+r, c=w*64+j*16+l15
#pragma unroll
  for (int m = 0; m < 2; m++)
#pragma unroll
    for (int j = 0; j < 4; j++)
#pragma unroll
      for (int r = 0; r < 4; r++) hreg[m][j][r] = 0.f;
  for (int i = tid; i < 32 * 264; i += 256) xh[i / 264][320 + i % 264] = 0;
  float b_r[4], b_z[4], b_in[4], b_hn[4];
#pragma unroll
  for (int j = 0; j < 4; j++) {
    int c = w * 64 + j * 16 + l15;
    b_r[j] = to_f(Bih[c]) + to_f(Bhh[c]);
    b_z[j] = to_f(Bih[256 + c]) + to_f(Bhh[256 + c]);
    b_in[j] = to_f(Bih[512 + c]);
    b_hn[j] = to_f(Bhh[512 + c]);
  }
  __syncthreads();

  for (int s = 0; s < 24; s++) {
    const int pos = dir ? 23 - s : s;
    if (tid < 32) idx[tid] = src[pos * 2048 + b0 + tid];
    __syncthreads();
    {  // gather x rows (32 x 320 shorts; 8 thr/row x 40 shorts)
      int r = tid >> 3, o = (tid & 7) * 40;
      const short* sp = (const short*)embE + (long long)idx[r] * 320 + o;
      short* dp = &xh[r][o];
#pragma unroll
      for (int u = 0; u < 5; u++)
        *(short8*)(dp + u * 8) = *(const short8*)(sp + u * 8);
    }
    __syncthreads();
    f32x4 accS[24];  // [m*12 + g*4 + j]
    f32x4 accN[8];   // [m*4 + j]
#pragma unroll
    for (int i = 0; i < 24; i++) accS[i] = 0.f;
#pragma unroll
    for (int i = 0; i < 8; i++) accN[i] = 0.f;
    {
      const short* bp[12];
#pragma unroll
      for (int g = 0; g < 3; g++)
#pragma unroll
        for (int j = 0; j < 4; j++)
          bp[g * 4 + j] =
              Ws + (long long)(g * 256 + w * 64 + j * 16 + l15) * 576 + q8;
      short8 bb0[12], bb1[12];
#pragma unroll
      for (int i = 0; i < 12; i++) bb0[i] = *(const short8*)bp[i];
      for (int kk = 0; kk < 18; kk += 2) {
        int k1 = (kk + 1) * 32;
#pragma unroll
        for (int i = 0; i < 12; i++) bb1[i] = *(const short8*)(bp[i] + k1);
        {
          short8 a0 = *(short8*)&xh[l15][kk * 32 + q8];
          short8 a1 = *(short8*)&xh[16 + l15][kk * 32 + q8];
#pragma unroll
          for (int i = 0; i < 12; i++) {
            accS[i] = MFMA(a0, bb0[i], accS[i]);
            accS[12 + i] = MFMA(a1, bb0[i], accS[12 + i]);
          }
        }
        if (kk + 2 < 18) {
          int k2 = (kk + 2) * 32;
#pragma unroll
          for (int i = 0; i < 12; i++) bb0[i] = *(const short8*)(bp[i] + k2);
        }
        {
          short8 a0 = *(short8*)&xh[l15][k1 + q8];
          short8 a1 = *(short8*)&xh[16 + l15][k1 + q8];
#pragma unroll
          for (int i = 0; i < 12; i++) {
            accS[i] = MFMA(a0, bb1[i], accS[i]);
            accS[12 + i] = MFMA(a1, bb1[i], accS[12 + i]);
          }
        }
      }
      const short* np = Whn + (long long)(w * 64 + l15) * 256 + q8;
      for (int k0 = 0; k0 < 256; k0 += 32) {
        short8 a0 = *(short8*)&xh[l15][320 + k0 + q8];
        short8 a1 = *(short8*)&xh[16 + l15][320 + k0 + q8];
#pragma unroll
        for (int j = 0; j < 4; j++) {
          short8 b = *(const short8*)(np + (long long)j * 16 * 256 + k0);
          accN[j] = MFMA(a0, b, accN[j]);
          accN[4 + j] = MFMA(a1, b, accN[4 + j]);
        }
      }
    }
    __syncthreads();  // all xh h-col reads done before cell writes
#pragma unroll
    for (int j = 0; j < 4; j++) {
      int c = w * 64 + j * 16 + l15;
#pragma unroll
      for (int m = 0; m < 2; m++) {
#pragma unroll
        for (int r = 0; r < 4; r++) {
          int row = m * 16 + qr + r;
          float Sr = accS[m * 12 + j][r];
          float Sz = accS[m * 12 + 4 + j][r];
          float Sn = accS[m * 12 + 8 + j][r];
          float hnr = accN[m * 4 + j][r];
          float rg = fsig(Sr + b_r[j]);
          float zg = fsig(Sz + b_z[j]);
          float nn = ftanh(Sn - hnr + b_in[j] + rg * (hnr + b_hn[j]));
          float o = (1.f - zg) * nn + zg * hreg[m][j][r];
          hreg[m][j][r] = o;
          xh[row][320 + c] = f2b(o);
          bse[((long long)(b0 + row) * 24 + pos) * 512 + dir * 256 + c] =
              __float2bfloat16(o);
        }
      }
    }
    __syncthreads();  // before next step's gather/idx overwrite
  }
#pragma unroll
  for (int j = 0; j < 4; j++) {
    int c = w * 64 + j * 16 + l15;
#pragma unroll
    for (int m = 0; m < 2; m++)
#pragma unroll
      for (int r = 0; r < 4; r++)
        hbf[(long long)(b0 + m * 16 + qr + r) * 512 + dir * 256 + c] =
            __float2bfloat16(hreg[m][j][r]);
  }
}

// ---- persistent decoder: block = 16 batch rows; 24 steps in-kernel.
// Per step: hWh GEMM -> LDS; energy/softmax; weighted from bse; main stacked
// GEMM S=[xg|h]@[Wih;Whh]^T (K=1088) + gh_n; cell (h in regs); logits GEMM.
__global__ __launch_bounds__(256, 1) void dec_persist(
    const bf16* __restrict__ embD, const int* __restrict__ trg,
    const short* __restrict__ WsD, const short* __restrict__ WhnD,
    const short* __restrict__ WhD, const short* __restrict__ W8T,
    const bf16* __restrict__ BihD, const bf16* __restrict__ BhhD,
    const bf16* __restrict__ B8, const bf16* __restrict__ Vv,
    const bf16* __restrict__ proj, const bf16* __restrict__ bse,
    const float* __restrict__ h_d, float* __restrict__ out) {
  const int b0 = blockIdx.x * 16;
  __shared__ short xgc[16][1096];  // emb 0:300 | wtd 300:812 | 0s | h 832:1088
  __shared__ short hwh[16][272];
  __shared__ float scs[16][24];
  __shared__ float aw[16][24];
  __shared__ int idx[16];
  const int tid = threadIdx.x, lane = tid & 63, w = tid >> 6;
  const int l15 = lane & 15, q8 = (lane >> 4) * 8, qr = (lane >> 4) * 4;

  float hreg[4][4];  // [j][r]: row=qr+r, c=w*64+j*16+l15
#pragma unroll
  for (int j = 0; j < 4; j++) {
    int c = w * 64 + j * 16 + l15;
#pragma unroll
    for (int r = 0; r < 4; r++) {
      float v = h_d[(long long)(b0 + qr + r) * 256 + c];
      hreg[j][r] = v;
      xgc[qr + r][832 + c] = f2b(v);
    }
  }
  for (int i = tid; i < 16 * 20; i += 256) xgc[i / 20][812 + i % 20] = 0;
  float vv0 = to_f(Vv[lane * 4]), vv1 = to_f(Vv[lane * 4 + 1]);
  float vv2 = to_f(Vv[lane * 4 + 2]), vv3 = to_f(Vv[lane * 4 + 3]);
  float b_r[4], b_z[4], b_in[4], b_hn[4];
#pragma unroll
  for (int j = 0; j < 4; j++) {
    int c = w * 64 + j * 16 + l15;
    b_r[j] = to_f(BihD[c]) + to_f(BhhD[c]);
    b_z[j] = to_f(BihD[256 + c]) + to_f(BhhD[256 + c]);
    b_in[j] = to_f(BihD[512 + c]);
    b_hn[j] = to_f(BhhD[512 + c]);
  }
  float bl8[2] = {to_f(B8[w * 32 + l15]), to_f(B8[w * 32 + 16 + l15])};
  __syncthreads();

  for (int t = 0; t < 24; t++) {
    if (tid < 16) idx[tid] = trg[t * 2048 + b0 + tid];
    __syncthreads();
    {  // emb gather (cols 0:300), 16 thr/row, short4 units
      int r = tid >> 4, u = tid & 15;
      const short* sp = (const short*)embD + (long long)idx[r] * 320;
#pragma unroll
      for (int c4 = 0; c4 < 5; c4++) {
        int cc = u + c4 * 16;
        if (cc < 75) *(s16x4*)&xgc[r][cc * 4] = *(const s16x4*)(sp + cc * 4);
      }
    }
    {  // hWh = h @ attn_Wh  (K=256, N=256)
      f32x4 accW[4];
#pragma unroll
      for (int j = 0; j < 4; j++) accW[j] = 0.f;
      const short* wp = WhD + (long long)(w * 64 + l15) * 256 + q8;
      for (int k0 = 0; k0 < 256; k0 += 32) {
        short8 a0 = *(short8*)&xgc[l15][832 + k0 + q8];
#pragma unroll
        for (int j = 0; j < 4; j++) {
          short8 b = *(const short8*)(wp + (long long)j * 16 * 256 + k0);
          accW[j] = MFMA(a0, b, accW[j]);
        }
      }
#pragma unroll
      for (int j = 0; j < 4; j++) {
        int c = w * 64 + j * 16 + l15;
#pragma unroll
        for (int r = 0; r < 4; r++) hwh[qr + r][c] = f2b(accW[j][r]);
      }
    }
    __syncthreads();
    // energy: 16 rows x 24 s tasks; wave covers s = {w,4+w,...}; lane: 4 dims
    for (int i = 0; i < 96; i++) {
      int row = i / 6, s = (i - (i / 6) * 6) * 4 + w;
      s16x4 hv = *(s16x4*)&hwh[row][lane * 4];
      s16x4 p4 = *(const s16x4*)((const short*)proj +
                                 (((long long)(b0 + row) * 24 + s) << 8) +
                                 lane * 4);
      float e = vv0 * ftanh(b2f(hv[0]) + b2f(p4[0])) +
                vv1 * ftanh(b2f(hv[1]) + b2f(p4[1])) +
                vv2 * ftanh(b2f(hv[2]) + b2f(p4[2])) +
                vv3 * ftanh(b2f(hv[3]) + b2f(p4[3]));
#pragma unroll
      for (int off = 32; off > 0; off >>= 1) e += __shfl_down(e, off, 64);
      if (lane == 0) scs[row][s] = e;
    }
    __syncthreads();
    if (tid < 16) {
      float mx = -1e30f;
#pragma unroll
      for (int s = 0; s < 24; s++) mx = fmaxf(mx, scs[tid][s]);
      float sm = 0.f, ex[24];
#pragma unroll
      for (int s = 0; s < 24; s++) {
        ex[s] = __expf(scs[tid][s] - mx);
        sm += ex[s];
      }
      float inv = __builtin_amdgcn_rcpf(sm);
#pragma unroll
      for (int s = 0; s < 24; s++) aw[tid][s] = ex[s] * inv;
    }
    __syncthreads();
    {  // weighted = sum_s a[s]*bse[b,s,:]; thread: row=tid>>4, 32 dims
      int row = tid >> 4, db = (tid & 15) * 32;
      float acc[32];
#pragma unroll
      for (int u = 0; u < 32; u++) acc[u] = 0.f;
      const short* bp =
          (const short*)bse + (long long)(b0 + row) * 24 * 512 + db;
      for (int s = 0; s < 24; s++) {
        float a = aw[row][s];
        const short* ps = bp + s * 512;
#pragma unroll
        for (int u8 = 0; u8 < 4; u8++) {
          short8 v8 = *(const short8*)(ps + u8 * 8);
#pragma unroll
          for (int d = 0; d < 8; d++) acc[u8 * 8 + d] += a * b2f(v8[d]);
        }
      }
#pragma unroll
      for (int u2 = 0; u2 < 16; u2++) {
        s16x2 o;
        o[0] = f2b(acc[u2 * 2]);
        o[1] = f2b(acc[u2 * 2 + 1]);
        *(s16x2*)&xgc[row][300 + db + u2 * 2] = o;
      }
    }
    __syncthreads();
    // main stacked GEMM (K=1088) + gh_n (K=256)
    f32x4 accS[12], accN[4];
#pragma unroll
    for (int i = 0; i < 12; i++) accS[i] = 0.f;
#pragma unroll
    for (int i = 0; i < 4; i++) accN[i] = 0.f;
    {
      const short* bp[12];
#pragma unroll
      for (int g = 0; g < 3; g++)
#pragma unroll
        for (int j = 0; j < 4; j++)
          bp[g * 4 + j] =
              WsD + (long long)(g * 256 + w * 64 + j * 16 + l15) * 1088 + q8;
      short8 bb0[12], bb1[12];
#pragma unroll
      for (int i = 0; i < 12; i++) bb0[i] = *(const short8*)bp[i];
      for (int kk = 0; kk < 34; kk += 2) {
        int k1 = (kk + 1) * 32;
#pragma unroll
        for (int i = 0; i < 12; i++) bb1[i] = *(const short8*)(bp[i] + k1);
        {
          short8 a0 = *(short8*)&xgc[l15][kk * 32 + q8];
#pragma unroll
          for (int i = 0; i < 12; i++) accS[i] = MFMA(a0, bb0[i], accS[i]);
        }
        if (kk + 2 < 34) {
          int k2 = (kk + 2) * 32;
#pragma unroll
          for (int i = 0; i < 12; i++) bb0[i] = *(const short8*)(bp[i] + k2);
        }
        {
          short8 a1 = *(short8*)&xgc[l15][k1 + q8];
#pragma unroll
          for (int i = 0; i < 12; i++) accS[i] = MFMA(a1, bb1[i], accS[i]);
        }
      }
      const short* np = WhnD + (long long)(w * 64 + l15) * 256 + q8;
      for (int k0 = 0; k0 < 256; k0 += 32) {
        short8 a0 = *(short8*)&xgc[l15][832 + k0 + q8];
#pragma unroll
        for (int j = 0; j < 4; j++) {
          short8 b = *(const short8*)(np + (long long)j * 16 * 256 + k0);
          accN[j] = MFMA(a0, b, accN[j]);
        }
      }
    }
    __syncthreads();  // xgc h-col reads done before cell writes
#pragma unroll
    for (int j = 0; j < 4; j++) {
      int c = w * 64 + j * 16 + l15;
#pragma unroll
      for (int r = 0; r < 4; r++) {
        float Sr = accS[j][r], Sz = accS[4 + j][r], Sn = accS[8 + j][r];
        float hnr = accN[j][r];
        float rg = fsig(Sr + b_r[j]);
        float zg = fsig(Sz + b_z[j]);
        float nn = ftanh(Sn - hnr + b_in[j] + rg * (hnr + b_hn[j]));
        float o = (1.f - zg) * nn + zg * hreg[j][r];
        hreg[j][r] = o;
        xgc[qr + r][832 + c] = f2b(o);
      }
    }
    __syncthreads();  // logits read updated h
    {  // logits = xgc @ fcW^T(k-permuted) + fcb -> out slice t+1
      f32x4 accL[2];
      accL[0] = 0.f;
      accL[1] = 0.f;
      const short* lp0 = W8T + (long long)(w * 32 + l15) * 1088 + q8;
      const short* lp1 = W8T + (long long)(w * 32 + 16 + l15) * 1088 + q8;
      short8 c00 = *(const short8*)lp0, c01 = *(const short8*)lp1;
      short8 c10, c11;
      for (int kk = 0; kk < 34; kk += 2) {
        int k1 = (kk + 1) * 32;
        c10 = *(const short8*)(lp0 + k1);
        c11 = *(const short8*)(lp1 + k1);
        {
          short8 a0 = *(short8*)&xgc[l15][kk * 32 + q8];
          accL[0] = MFMA(a0, c00, accL[0]);
          accL[1] = MFMA(a0, c01, accL[1]);
        }
        if (kk + 2 < 34) {
          int k2 = (kk + 2) * 32;
          c00 = *(const short8*)(lp0 + k2);
          c01 = *(const short8*)(lp1 + k2);
        }
        {
          short8 a1 = *(short8*)&xgc[l15][k1 + q8];
          accL[0] = MFMA(a1, c10, accL[0]);
          accL[1] = MFMA(a1, c11, accL[1]);
        }
      }
      float* ob = out + ((long long)(t + 1) * 2048 + b0) * 128;
#pragma unroll
      for (int j2 = 0; j2 < 2; j2++) {
        int n = w * 32 + j2 * 16 + l15;
#pragma unroll
        for (int r = 0; r < 4; r++)
          ob[(long long)(qr + r) * 128 + n] = accL[j2][r] + bl8[j2];
      }
    }
    __syncthreads();  // before next step's emb/weighted overwrite
  }
}

__global__ void sentinel_kernel(float* out, int n) {
  int i = blockIdx.x * 256 + threadIdx.x;
  if (i < n) out[i] = 123.0f;
}

extern "C" void kernel_launch(void* const* d_in, const int* in_sizes, int n_in,
                              void* d_out, int out_size, void* d_ws,
                              size_t ws_size, hipStream_t stream) {
  const int B = 2048, VOUT = 128;
  const int* src = (const int*)d_in[0];
  const int* trg = (const int*)d_in[1];
  const void* enc_emb = d_in[2];
  const void* enc_Wih_f = d_in[3];
  const void* enc_Whh_f = d_in[4];
  const void* enc_bih_f = d_in[5];
  const void* enc_bhh_f = d_in[6];
  const void* enc_Wih_b = d_in[7];
  const void* enc_Whh_b = d_in[8];
  const void* enc_bih_b = d_in[9];
  const void* enc_bhh_b = d_in[10];
  const void* enc_fcW = d_in[11];
  const void* enc_fcb = d_in[12];
  const void* attn_Wh = d_in[13];
  const void* attn_We = d_in[14];
  const void* attn_b = d_in[15];
  const void* attn_v = d_in[16];
  const void* dec_emb = d_in[17];
  const void* dec_Wih = d_in[18];
  const void* dec_Whh = d_in[19];
  const void* dec_bih = d_in[20];
  const void* dec_bhh = d_in[21];
  const void* fcW = d_in[22];
  const void* fcb = d_in[23];
  float* out = (float*)d_out;

  size_t need = 0;
  auto place = [&](size_t bytes) {
    size_t off = need;
    need += (bytes + 255) & ~(size_t)255;
    return off;
  };
  size_t o_flag = place(256);
  size_t o_w0 = need;
  size_t oEmbE = place(64 * 320 * 2);
  size_t oEmbD = place(128 * 320 * 2);
  size_t oWsF = place(768 * 576 * 2);
  size_t oWsB = place(768 * 576 * 2);
  size_t oWhnF = place(256 * 256 * 2);
  size_t oWhnB = place(256 * 256 * 2);
  size_t oWT5 = place(256 * 512 * 2);
  size_t oWT6 = place(256 * 512 * 2);
  size_t oWsD = place(768 * 1088 * 2);
  size_t oWhnD = place(256 * 256 * 2);
  size_t oWhD = place(256 * 256 * 2);
  size_t oW8T = place(128 * 1088 * 2);
  size_t oBihF = place(768 * 2), oBhhF = place(768 * 2);
  size_t oBihB = place(768 * 2), oBhhB = place(768 * 2);
  size_t oB5 = place(256 * 2), oB6 = place(256 * 2);
  size_t oBihD = place(768 * 2), oBhhD = place(768 * 2);
  size_t oB8 = place(128 * 2), oVv = place(256 * 2);
  size_t o_w1 = need;
  size_t o_bse = place((size_t)B * 24 * 512 * 2);
  size_t o_proj = place((size_t)B * 24 * 256 * 2);
  size_t o_hbf = place((size_t)B * 512 * 2);
  size_t o_hd = place((size_t)B * 256 * 4);

  if (ws_size < need) {
    sentinel_kernel<<<(out_size + 255) / 256, 256, 0, stream>>>(out, out_size);
    return;
  }
  char* base = (char*)d_ws;
  unsigned* dflag = (unsigned*)(base + o_flag);
  bf16* embE = (bf16*)(base + oEmbE);
  bf16* embD = (bf16*)(base + oEmbD);
  short* WsF = (short*)(base + oWsF);
  short* WsB = (short*)(base + oWsB);
  short* WhnF = (short*)(base + oWhnF);
  short* WhnB = (short*)(base + oWhnB);
  short* WT5 = (short*)(base + oWT5);
  short* WT6 = (short*)(base + oWT6);
  short* WsD = (short*)(base + oWsD);
  short* WhnD = (short*)(base + oWhnD);
  short* WhD = (short*)(base + oWhD);
  short* W8T = (short*)(base + oW8T);
  bf16 *BihF = (bf16*)(base + oBihF), *BhhF = (bf16*)(base + oBhhF);
  bf16 *BihB = (bf16*)(base + oBihB), *BhhB = (bf16*)(base + oBhhB);
  bf16 *B5 = (bf16*)(base + oB5), *B6 = (bf16*)(base + oB6);
  bf16 *BihD = (bf16*)(base + oBihD), *BhhD = (bf16*)(base + oBhhD);
  bf16 *B8 = (bf16*)(base + oB8), *Vv = (bf16*)(base + oVv);
  bf16* bse = (bf16*)(base + o_bse);
  bf16* proj = (bf16*)(base + o_proj);
  bf16* hbf = (bf16*)(base + o_hbf);
  float* h_d = (float*)(base + o_hd);

  detect_kernel<<<1, 256, 0, stream>>>(enc_emb, dflag);
  (void)hipMemsetAsync(base + o_w0, 0, o_w1 - o_w0, stream);

  PrepArgs pa;
  int ns = 0;
  long long tot = 0;
  auto seg = [&](const void* s, long long soff, short* dst, int scols,
                 int sstride, int dstride, int transp, long long count) {
    pa.src[ns] = s;
    pa.soff[ns] = soff;
    pa.dst[ns] = dst;
    pa.scols[ns] = scols;
    pa.sstride[ns] = sstride;
    pa.dstride[ns] = dstride;
    pa.transp[ns] = transp;
    pa.prefix[ns] = tot;
    tot += count;
    ns++;
  };
  seg(enc_emb, 0, (short*)embE, 300, 300, 320, 0, 64 * 300);
  seg(dec_emb, 0, (short*)embD, 300, 300, 320, 0, 128 * 300);
  seg(enc_Wih_f, 0, WsF, 768, 768, 576, 1, 300 * 768);
  seg(enc_Whh_f, 0, WsF + 320, 768, 768, 576, 1, 256 * 768);
  seg(enc_Wih_b, 0, WsB, 768, 768, 576, 1, 300 * 768);
  seg(enc_Whh_b, 0, WsB + 320, 768, 768, 576, 1, 256 * 768);
  seg(enc_Whh_f, 512, WhnF, 256, 768, 256, 1, 256 * 256);
  seg(enc_Whh_b, 512, WhnB, 256, 768, 256, 1, 256 * 256);
  seg(enc_fcW, 0, WT5, 256, 256, 512, 1, 512 * 256);
  seg(attn_We, 0, WT6, 256, 256, 512, 1, 512 * 256);
  seg(dec_Wih, 0, WsD, 768, 768, 1088, 1, 812 * 768);
  seg(dec_Whh, 0, WsD + 832, 768, 768, 1088, 1, 256 * 768);
  seg(dec_Whh, 512, WhnD, 256, 768, 256, 1, 256 * 256);
  seg(attn_Wh, 0, WhD, 256, 256, 256, 1, 256 * 256);
  // fcW^T k-permuted: emb<-rows 768:1068, wtd<-256:768, hn<-0:256
  seg(fcW, (long long)768 * 128, W8T, 128, 128, 1088, 1, 300 * 128);
  seg(fcW, (long long)256 * 128, W8T + 300, 128, 128, 1088, 1, 512 * 128);
  seg(fcW, 0, W8T + 832, 128, 128, 1088, 1, 256 * 128);
  seg(enc_bih_f, 0, (short*)BihF, 768, 768, 768, 0, 768);
  seg(enc_bhh_f, 0, (short*)BhhF, 768, 768, 768, 0, 768);
  seg(enc_bih_b, 0, (short*)BihB, 768, 768, 768, 0, 768);
  seg(enc_bhh_b, 0, (short*)BhhB, 768, 768, 768, 0, 768);
  seg(enc_fcb, 0, (short*)B5, 256, 256, 256, 0, 256);
  seg(attn_b, 0, (short*)B6, 256, 256, 256, 0, 256);
  seg(dec_bih, 0, (short*)BihD, 768, 768, 768, 0, 768);
  seg(dec_bhh, 0, (short*)BhhD, 768, 768, 768, 0, 768);
  seg(fcb, 0, (short*)B8, 128, 128, 128, 0, 128);
  seg(attn_v, 0, (short*)Vv, 256, 256, 256, 0, 256);
  pa.prefix[ns] = tot;
  pa.nseg = ns;
  prep_kernel<<<(int)((tot + 255) / 256), 256, 0, stream>>>(pa, dflag);

  (void)hipMemsetAsync(out, 0, (size_t)B * VOUT * 4, stream);  // outputs[0]=0

  enc_persist<<<dim3(64, 2), 256, 0, stream>>>(embE, src, WsF, WsB, WhnF,
                                               WhnB, BihF, BhhF, BihB, BhhB,
                                               bse, hbf);
  {
    GJobs a{};
    a.j[0] = {hbf, nullptr, WT5, B5, h_d, nullptr, 512, 512, 512, B, 256, 4};
    a.j[1] = {bse, nullptr, WT6, B6, nullptr, proj, 512, 512, 512, B * 24, 256,
              0};
    mj_gemm<<<dim3(2, 384, 2), 256, 0, stream>>>(a);
  }
  dec_persist<<<128, 256, 0, stream>>>(embD, trg, WsD, WhnD, WhD, W8T, BihD,
                                       BhhD, B8, Vv, proj, bse, h_d, out);
}

// Round 10
// 6299.477 us; speedup vs baseline: 1.3191x; 1.3191x over previous
//
#include <hip/hip_runtime.h>
#include <hip/hip_bf16.h>

typedef __hip_bfloat16 bf16;
typedef __attribute__((ext_vector_type(8))) short short8;
typedef __attribute__((ext_vector_type(4))) float f32x4;

__device__ __forceinline__ float to_f(float x) { return x; }
__device__ __forceinline__ float to_f(bf16 x) { return __bfloat162float(x); }
__device__ __forceinline__ float ldp(const void* p, size_t i, bool f32) {
  return f32 ? ((const float*)p)[i] : __bfloat162float(((const bf16*)p)[i]);
}
__device__ __forceinline__ short f2b(float f) {
  bf16 h = __float2bfloat16(f);
  return *reinterpret_cast<short*>(&h);
}

// dtype probe: f32 data read as u16 pairs shows implausible bf16 exponents.
__global__ void detect_kernel(const void* __restrict__ probe,
                              unsigned* __restrict__ flag) {
  __shared__ int sbad;
  if (threadIdx.x == 0) sbad = 0;
  __syncthreads();
  const unsigned short* u = (const unsigned short*)probe;
  int bad = 0;
  for (int i = threadIdx.x; i < 2048; i += 256) {
    unsigned short w = u[i];
    unsigned e = (w >> 7) & 0xFFu;
    bool plaus = (w == 0) || (w == 0x8000u) || (e >= 0x60u && e <= 0x7Eu);
    if (!plaus) bad++;
  }
  atomicAdd(&sbad, bad);
  __syncthreads();
  if (threadIdx.x == 0) *flag = (sbad > 100) ? 1u : 0u;
}

// ---- weight prep: params (f32|bf16) -> bf16 ws; optional transpose ----
#define MAXSEG 24
struct PrepArgs {
  int nseg;
  const void* src[MAXSEG];
  long long soff[MAXSEG];
  short* dst[MAXSEG];
  int scols[MAXSEG];
  int dstride[MAXSEG];
  int transp[MAXSEG];
  long long prefix[MAXSEG + 1];
};
__global__ void prep_kernel(PrepArgs a, const unsigned* __restrict__ dflag) {
  const bool isf32 = (*dflag != 0u);
  long long i = (long long)blockIdx.x * 256 + threadIdx.x;
  if (i >= a.prefix[a.nseg]) return;
  int s = 0;
  while (i >= a.prefix[s + 1]) s++;
  long long loc = i - a.prefix[s];
  long long r = loc / a.scols[s], c = loc % a.scols[s];
  float v = a.src[s] ? ldp(a.src[s], (size_t)(a.soff[s] + loc), isf32) : 0.f;
  long long idx = a.transp[s] ? (c * a.dstride[s] + r) : (r * a.dstride[s] + c);
  a.dst[s][idx] = f2b(v);
}

// ---- multi-job MFMA GEMM, 128x128 tile, XCD-swizzled grid, LDS-staged ----
// ---- full-line epilogue writes. flags: 1=gather, 4=tanh. ----
struct GJob {
  const bf16* A;
  const int* rowidx;
  const short* WT;
  const bf16* bias;
  float* Cf;
  bf16* Ch;
  int lda, wst, K, M, N, flags;
};
struct GJobs {
  GJob j[4];
  int gx;  // n-tiles in the (flattened) grid
};

__global__ __launch_bounds__(256) void mj_gemm(GJobs args) {
  GJob jb = args.j[blockIdx.z];
  // XCD swizzle: linear%8 == m%8 -> all n-tiles of an m-strip share one XCD L2
  const int gx = args.gx;
  int bx = blockIdx.x;
  int chunk = bx / (8 * gx);
  int rem = bx - chunk * 8 * gx;
  const int m0 = (chunk * 8 + (rem & 7)) * 128;
  const int n0 = (rem >> 3) * 128;
  if (n0 >= jb.N || m0 >= jb.M) return;
  __shared__ short smem[10240];  // As[128][40] | Bs[128][40]; reused as stage
  short* As = smem;
  short* Bs = smem + 5120;
  __shared__ int rows[128];
  const int tid = threadIdx.x, lane = tid & 63, wave = tid >> 6;
  const int l15 = lane & 15, q8 = (lane >> 4) * 8, qr = (lane >> 4) * 4;
  const int srow = tid >> 1, skoff = (tid & 1) * 16;
  const int wr = (wave >> 1) * 64, wc = (wave & 1) * 64;
  if (jb.flags & 1) {
    if (tid < 128) rows[tid] = jb.rowidx[m0 + tid];
    __syncthreads();
  }
  const long long arow =
      (jb.flags & 1) ? (long long)rows[srow] : (long long)(m0 + srow);
  const short* abase = (const short*)jb.A + arow * jb.lda + skoff;
  const short* bbase = jb.WT + (long long)(n0 + srow) * jb.wst + skoff;
  f32x4 acc[4][4];
#pragma unroll
  for (int i = 0; i < 4; i++)
#pragma unroll
    for (int j = 0; j < 4; j++) acc[i][j] = 0.f;
  const int K = jb.K;
  short8 a0 = *(const short8*)(abase);
  short8 a1 = *(const short8*)(abase + 8);
  short8 b0 = *(const short8*)(bbase);
  short8 b1 = *(const short8*)(bbase + 8);
  for (int k0 = 0; k0 < K; k0 += 32) {
    __syncthreads();
    *(short8*)&As[srow * 40 + skoff] = a0;
    *(short8*)&As[srow * 40 + skoff + 8] = a1;
    *(short8*)&Bs[srow * 40 + skoff] = b0;
    *(short8*)&Bs[srow * 40 + skoff + 8] = b1;
    __syncthreads();
    int kn = (k0 + 32 < K) ? k0 + 32 : k0;
    a0 = *(const short8*)(abase + kn);
    a1 = *(const short8*)(abase + kn + 8);
    b0 = *(const short8*)(bbase + kn);
    b1 = *(const short8*)(bbase + kn + 8);
    short8 af[4], bfr[4];
#pragma unroll
    for (int i = 0; i < 4; i++)
      af[i] = *(short8*)&As[(wr + i * 16 + l15) * 40 + q8];
#pragma unroll
    for (int j = 0; j < 4; j++)
      bfr[j] = *(short8*)&Bs[(wc + j * 16 + l15) * 40 + q8];
#pragma unroll
    for (int i = 0; i < 4; i++)
#pragma unroll
      for (int j = 0; j < 4; j++)
        acc[i][j] =
            __builtin_amdgcn_mfma_f32_16x16x32_bf16(af[i], bfr[j], acc[i][j],
                                                    0, 0, 0);
  }
  // bias + act folded into acc
#pragma unroll
  for (int j = 0; j < 4; j++) {
    float bv = jb.bias ? to_f(jb.bias[n0 + wc + j * 16 + l15]) : 0.f;
#pragma unroll
    for (int i = 0; i < 4; i++)
#pragma unroll
      for (int r = 0; r < 4; r++) {
        float v = acc[i][j][r] + bv;
        acc[i][j][r] = (jb.flags & 4) ? tanhf(v) : v;
      }
  }
  const int N = jb.N;
  // LDS-staged epilogue: 4 passes of 32 rows -> full-line coalesced writes
  if (jb.Cf) {
    float* stf = (float*)smem;  // [32][136]
    for (int p = 0; p < 4; p++) {
      __syncthreads();
      if ((wr >> 6) == (p >> 1)) {
        int i0 = p * 2 - (wr >> 4);
#pragma unroll
        for (int u = 0; u < 2; u++) {
          int ii = i0 + u;
          int rl = wr + ii * 16 + qr - p * 32;
#pragma unroll
          for (int j = 0; j < 4; j++)
#pragma unroll
            for (int r = 0; r < 4; r++)
              stf[(rl + r) * 136 + wc + j * 16 + l15] = acc[ii][j][r];
        }
      }
      __syncthreads();
      int rl = tid >> 3, c0 = (tid & 7) * 16;
      float* dst = jb.Cf + (long long)(m0 + p * 32 + rl) * N + n0 + c0;
      const float* sp = &stf[rl * 136 + c0];
#pragma unroll
      for (int u = 0; u < 4; u++)
        *(float4*)(dst + u * 4) = *(const float4*)(sp + u * 4);
    }
  }
  if (jb.Ch) {
    short* sth = smem;  // [32][136]
    for (int p = 0; p < 4; p++) {
      __syncthreads();
      if ((wr >> 6) == (p >> 1)) {
        int i0 = p * 2 - (wr >> 4);
#pragma unroll
        for (int u = 0; u < 2; u++) {
          int ii = i0 + u;
          int rl = wr + ii * 16 + qr - p * 32;
#pragma unroll
          for (int j = 0; j < 4; j++)
#pragma unroll
            for (int r = 0; r < 4; r++)
              sth[(rl + r) * 136 + wc + j * 16 + l15] = f2b(acc[ii][j][r]);
        }
      }
      __syncthreads();
      int rl = tid >> 3, c0 = (tid & 7) * 16;
      short* dst = (short*)jb.Ch + (long long)(m0 + p * 32 + rl) * N + n0 + c0;
      const short* sp = &sth[rl * 136 + c0];
      *(short8*)dst = *(const short8*)sp;
      *(short8*)(dst + 8) = *(const short8*)(sp + 8);
    }
  }
}

// encoder dual-direction GRU cell. U = 4 segs of (B,768) bf16:
// [gi_f, gh_f, gi_b, gh_b]. dir = blockIdx.y.
__global__ __launch_bounds__(256) void enc_cell(
    const bf16* __restrict__ U, float* __restrict__ hfb,
    bf16* __restrict__ hbf, bf16* __restrict__ bse, int s) {
  int dir = blockIdx.y, b = blockIdx.x, i = threadIdx.x;
  const bf16* gi = U + ((long long)(dir * 2) * 2048 + b) * 768;
  const bf16* gh = U + ((long long)(dir * 2 + 1) * 2048 + b) * 768;
  float ir = to_f(gi[i]), iz = to_f(gi[256 + i]), in_ = to_f(gi[512 + i]);
  float hr = to_f(gh[i]), hz = to_f(gh[256 + i]), hn = to_f(gh[512 + i]);
  long long hidx = (long long)b * 512 + dir * 256 + i;
  float hv = hfb[hidx];
  float r = 1.f / (1.f + expf(-(ir + hr)));
  float z = 1.f / (1.f + expf(-(iz + hz)));
  float n = tanhf(in_ + r * hn);
  float o = (1.f - z) * n + z * hv;
  hfb[hidx] = o;
  hbf[hidx] = __float2bfloat16(o);
  int pos = dir ? (23 - s) : s;
  bse[(long long)b * (24 * 512) + pos * 512 + dir * 256 + i] =
      __float2bfloat16(o);
}

// decoder GRU cell: gi (B,768) bf16, ghw (B,1024) bf16 (first 768 = gh).
// xgc stride 1088; writes hn into cols 812:1068.
__global__ __launch_bounds__(256) void dec_cell(
    const bf16* __restrict__ gi, const bf16* __restrict__ ghw,
    float* __restrict__ h_d, bf16* __restrict__ hdbf, bf16* __restrict__ xgc) {
  int b = blockIdx.x, i = threadIdx.x;
  const bf16* gib = gi + (long long)b * 768;
  const bf16* ghb = ghw + (long long)b * 1024;
  float ir = to_f(gib[i]), iz = to_f(gib[256 + i]), in_ = to_f(gib[512 + i]);
  float hr = to_f(ghb[i]), hz = to_f(ghb[256 + i]), hn = to_f(ghb[512 + i]);
  float hv = h_d[(long long)b * 256 + i];
  float r = 1.f / (1.f + expf(-(ir + hr)));
  float z = 1.f / (1.f + expf(-(iz + hz)));
  float n = tanhf(in_ + r * hn);
  float o = (1.f - z) * n + z * hv;
  h_d[(long long)b * 256 + i] = o;
  hdbf[(long long)b * 256 + i] = __float2bfloat16(o);
  xgc[(long long)b * 1088 + 812 + i] = __float2bfloat16(o);
}

// attention + decoder embedding. hWh = ghw[:,768:1024]. embD prepped bf16
// (stride 320). Writes xgc[:,0:300]=emb, [:,300:812]=weighted (stride 1088).
__global__ __launch_bounds__(256) void attn_kernel(
    const bf16* __restrict__ ghw, const bf16* __restrict__ proj,
    const bf16* __restrict__ bse, const void* __restrict__ v,
    const int* __restrict__ trg_t, const bf16* __restrict__ embD,
    bf16* __restrict__ xgc, const unsigned* __restrict__ dflag) {
  const bool isf32 = (*dflag != 0u);
  int b = blockIdx.x, tid = threadIdx.x;
  int wave = tid >> 6, lane = tid & 63;
  __shared__ float partial[24][4];
  __shared__ float aw[24];
  float vh = to_f(ghw[(long long)b * 1024 + 768 + tid]);
  float vv = ldp(v, tid, isf32);
  const bf16* pb = proj + (long long)b * 24 * 256;
#pragma unroll 4
  for (int s = 0; s < 24; s++) {
    float e = tanhf(vh + __bfloat162float(pb[s * 256 + tid]));
    float t = vv * e;
#pragma unroll
    for (int off = 32; off > 0; off >>= 1) t += __shfl_down(t, off, 64);
    if (lane == 0) partial[s][wave] = t;
  }
  __syncthreads();
  if (tid == 0) {
    float sc[24];
    float mx = -1e30f;
    for (int s = 0; s < 24; s++) {
      float xv = partial[s][0] + partial[s][1] + partial[s][2] + partial[s][3];
      sc[s] = xv;
      mx = fmaxf(mx, xv);
    }
    float sum = 0.f;
    for (int s = 0; s < 24; s++) {
      sc[s] = expf(sc[s] - mx);
      sum += sc[s];
    }
    float inv = 1.f / sum;
    for (int s = 0; s < 24; s++) aw[s] = sc[s] * inv;
  }
  __syncthreads();
  const bf16* eb = bse + (long long)b * 24 * 512;
  float w0 = 0.f, w1 = 0.f;
#pragma unroll 4
  for (int s = 0; s < 24; s++) {
    float a = aw[s];
    w0 += a * __bfloat162float(eb[s * 512 + tid]);
    w1 += a * __bfloat162float(eb[s * 512 + 256 + tid]);
  }
  bf16* xb = xgc + (long long)b * 1088;
  xb[300 + tid] = __float2bfloat16(w0);
  xb[556 + tid] = __float2bfloat16(w1);
  long long row = trg_t[b];
  for (int e = tid; e < 300; e += 256) xb[e] = embD[row * 320 + e];
}

__global__ void sentinel_kernel(float* out, int n) {
  int i = blockIdx.x * 256 + threadIdx.x;
  if (i < n) out[i] = 123.0f;
}

extern "C" void kernel_launch(void* const* d_in, const int* in_sizes, int n_in,
                              void* d_out, int out_size, void* d_ws,
                              size_t ws_size, hipStream_t stream) {
  const int B = 2048, S = 24, T = 25, VOUT = 128;
  const int* src = (const int*)d_in[0];
  const int* trg = (const int*)d_in[1];
  const void* enc_emb = d_in[2];
  const void* enc_Wih_f = d_in[3];
  const void* enc_Whh_f = d_in[4];
  const void* enc_bih_f = d_in[5];
  const void* enc_bhh_f = d_in[6];
  const void* enc_Wih_b = d_in[7];
  const void* enc_Whh_b = d_in[8];
  const void* enc_bih_b = d_in[9];
  const void* enc_bhh_b = d_in[10];
  const void* enc_fcW = d_in[11];
  const void* enc_fcb = d_in[12];
  const void* attn_Wh = d_in[13];
  const void* attn_We = d_in[14];
  const void* attn_b = d_in[15];
  const void* attn_v = d_in[16];
  const void* dec_emb = d_in[17];
  const void* dec_Wih = d_in[18];
  const void* dec_Whh = d_in[19];
  const void* dec_bih = d_in[20];
  const void* dec_bhh = d_in[21];
  const void* fcW = d_in[22];
  const void* fcb = d_in[23];
  float* out = (float*)d_out;

  size_t need = 0;
  auto place = [&](size_t bytes) {
    size_t off = need;
    need += (bytes + 255) & ~(size_t)255;
    return off;
  };
  size_t o_flag = place(256);
  size_t o_wstart = need;
  size_t oEmbE = place(64 * 320 * 2);
  size_t oEmbD = place(128 * 320 * 2);
  size_t oWT1 = place(768 * 320 * 2);
  size_t oWT2 = place(768 * 256 * 2);
  size_t oWT3 = place(768 * 320 * 2);
  size_t oWT4 = place(768 * 256 * 2);
  size_t oWT5 = place(256 * 512 * 2);
  size_t oWT6 = place(256 * 512 * 2);
  size_t oWcT = place(1024 * 256 * 2);
  size_t oW7T = place(768 * 832 * 2);
  size_t oW8T = place(128 * 1088 * 2);
  size_t oB1 = place(768 * 2), oB2 = place(768 * 2);
  size_t oB3 = place(768 * 2), oB4 = place(768 * 2);
  size_t oB5 = place(256 * 2), oB6 = place(256 * 2);
  size_t oB7 = place(768 * 2), oBc = place(1024 * 2), oB8 = place(128 * 2);
  size_t o_wend = need;
  size_t o_bse = place((size_t)B * S * 512 * 2);
  size_t o_proj = place((size_t)B * S * 256 * 2);
  size_t o_U = place((size_t)4 * B * 768 * 2);
  size_t o_hfb = place((size_t)B * 512 * 4);
  size_t o_hbf = place((size_t)B * 512 * 2);
  size_t o_hd = place((size_t)B * 256 * 4);
  size_t o_hdbf = place((size_t)B * 256 * 2);

  if (ws_size < need) {
    sentinel_kernel<<<(out_size + 255) / 256, 256, 0, stream>>>(out, out_size);
    return;
  }

  char* base = (char*)d_ws;
  unsigned* dflag = (unsigned*)(base + o_flag);
  bf16* embE = (bf16*)(base + oEmbE);
  bf16* embD = (bf16*)(base + oEmbD);
  short* WT1 = (short*)(base + oWT1);
  short* WT2 = (short*)(base + oWT2);
  short* WT3 = (short*)(base + oWT3);
  short* WT4 = (short*)(base + oWT4);
  short* WT5 = (short*)(base + oWT5);
  short* WT6 = (short*)(base + oWT6);
  short* WcT = (short*)(base + oWcT);
  short* W7T = (short*)(base + oW7T);
  short* W8T = (short*)(base + oW8T);
  bf16 *B1 = (bf16*)(base + oB1), *B2 = (bf16*)(base + oB2);
  bf16 *B3 = (bf16*)(base + oB3), *B4 = (bf16*)(base + oB4);
  bf16 *B5 = (bf16*)(base + oB5), *B6 = (bf16*)(base + oB6);
  bf16 *B7 = (bf16*)(base + oB7), *Bc = (bf16*)(base + oBc);
  bf16* B8 = (bf16*)(base + oB8);
  bf16* bse = (bf16*)(base + o_bse);
  bf16* proj = (bf16*)(base + o_proj);
  bf16* U = (bf16*)(base + o_U);
  float* hfb = (float*)(base + o_hfb);
  bf16* hbf = (bf16*)(base + o_hbf);
  float* h_d = (float*)(base + o_hd);
  bf16* hdbf = (bf16*)(base + o_hdbf);
  bf16* gi = U;                                        // (B,768)
  bf16* ghw = U + (size_t)B * 768;                     // (B,1024)
  bf16* xgc = U + (size_t)B * 768 + (size_t)B * 1024;  // (B,1088)

  detect_kernel<<<1, 256, 0, stream>>>(enc_emb, dflag);
  (void)hipMemsetAsync(base + o_wstart, 0, o_wend - o_wstart, stream);

  PrepArgs pa;
  int ns = 0;
  long long tot = 0;
  auto seg = [&](const void* s, long long soff, short* dst, int scols,
                 int dstride, int transp, long long count) {
    pa.src[ns] = s;
    pa.soff[ns] = soff;
    pa.dst[ns] = dst;
    pa.scols[ns] = scols;
    pa.dstride[ns] = dstride;
    pa.transp[ns] = transp;
    pa.prefix[ns] = tot;
    tot += count;
    ns++;
  };
  seg(enc_emb, 0, (short*)embE, 300, 320, 0, 64 * 300);
  seg(dec_emb, 0, (short*)embD, 300, 320, 0, 128 * 300);
  seg(enc_Wih_f, 0, WT1, 768, 320, 1, 230400);
  seg(enc_Whh_f, 0, WT2, 768, 256, 1, 196608);
  seg(enc_Wih_b, 0, WT3, 768, 320, 1, 230400);
  seg(enc_Whh_b, 0, WT4, 768, 256, 1, 196608);
  seg(enc_fcW, 0, WT5, 256, 512, 1, 131072);
  seg(attn_We, 0, WT6, 256, 512, 1, 131072);
  seg(dec_Whh, 0, WcT, 768, 256, 1, 196608);
  seg(attn_Wh, 0, WcT + 768 * 256, 256, 256, 1, 65536);
  seg(dec_Wih, 0, W7T, 768, 832, 1, 623616);
  seg(fcW, (long long)768 * 128, W8T, 128, 1088, 1, 300 * 128);
  seg(fcW, (long long)256 * 128, W8T + 300, 128, 1088, 1, 512 * 128);
  seg(fcW, 0, W8T + 812, 128, 1088, 1, 256 * 128);
  seg(enc_bih_f, 0, (short*)B1, 768, 768, 0, 768);
  seg(enc_bhh_f, 0, (short*)B2, 768, 768, 0, 768);
  seg(enc_bih_b, 0, (short*)B3, 768, 768, 0, 768);
  seg(enc_bhh_b, 0, (short*)B4, 768, 768, 0, 768);
  seg(enc_fcb, 0, (short*)B5, 256, 256, 0, 256);
  seg(attn_b, 0, (short*)B6, 256, 256, 0, 256);
  seg(dec_bih, 0, (short*)B7, 768, 768, 0, 768);
  seg(dec_bhh, 0, (short*)Bc, 768, 768, 0, 768);  // Bc[768:1024] stays 0
  seg(fcb, 0, (short*)B8, 128, 128, 0, 128);
  pa.prefix[ns] = tot;
  pa.nseg = ns;
  prep_kernel<<<(int)((tot + 255) / 256), 256, 0, stream>>>(pa, dflag);

  (void)hipMemsetAsync(hfb, 0, (size_t)B * 512 * 4, stream);
  (void)hipMemsetAsync(hbf, 0, (size_t)B * 512 * 2, stream);
  (void)hipMemsetAsync(out, 0, (size_t)B * VOUT * 4, stream);  // outputs[0]=0

  auto launch = [&](const GJob* jobs, int nj, int gx, int gy) {
    GJobs a{};
    for (int i = 0; i < nj; i++) a.j[i] = jobs[i];
    a.gx = gx;
    mj_gemm<<<dim3(gx * gy, 1, nj), 256, 0, stream>>>(a);
  };
  bf16* U1 = U + (size_t)B * 768;
  bf16* U2 = U + (size_t)2 * B * 768;
  bf16* U3 = U + (size_t)3 * B * 768;

  // ---- encoder: per step one 4-job GEMM + cell ----
  for (int s = 0; s < S; s++) {
    GJob j[4];
    j[0] = {embE, src + (size_t)s * B, WT1, B1, nullptr, U, 320, 320, 320, B,
            768, 1};
    j[1] = {hbf, nullptr, WT2, B2, nullptr, U1, 512, 256, 256, B, 768, 0};
    j[2] = {embE, src + (size_t)(S - 1 - s) * B, WT3, B3, nullptr, U2, 320,
            320, 320, B, 768, 1};
    j[3] = {hbf + 256, nullptr, WT4, B4, nullptr, U3, 512, 256, 256, B, 768,
            0};
    launch(j, 4, 6, 16);
    enc_cell<<<dim3(B, 2), 256, 0, stream>>>(U, hfb, hbf, bse, s);
  }
  // hidden = tanh([h_f,h_b]@enc_fcW+b) -> h_d/hdbf; proj = bse@attn_We+attn_b
  {
    GJob j[2];
    j[0] = {hbf, nullptr, WT5, B5, h_d, hdbf, 512, 512, 512, B, 256, 4};
    j[1] = {bse, nullptr, WT6, B6, nullptr, proj, 512, 512, 512, B * S, 256,
            0};
    launch(j, 2, 2, 384);
  }

  // ---- decoder ----
  auto wc_job = [&]() -> GJob {
    return {hdbf, nullptr, WcT, Bc, nullptr, ghw, 256, 256, 256, B, 1024, 0};
  };
  {
    GJob j0 = wc_job();
    launch(&j0, 1, 8, 16);
  }
  for (int t = 0; t < T - 1; t++) {
    attn_kernel<<<B, 256, 0, stream>>>(ghw, proj, bse, attn_v,
                                       trg + (size_t)t * B, embD, xgc, dflag);
    GJob jw = {xgc, nullptr, W7T, B7, nullptr, gi, 1088, 832, 832, B, 768, 0};
    launch(&jw, 1, 6, 16);
    dec_cell<<<B, 256, 0, stream>>>(gi, ghw, h_d, hdbf, xgc);
    GJob jf[2];
    jf[0] = {xgc, nullptr, W8T, B8, out + (size_t)(t + 1) * B * VOUT, nullptr,
             1088, 1088, 1088, B, 128, 0};
    if (t < T - 2) {
      jf[1] = wc_job();
      launch(jf, 2, 8, 16);
    } else {
      launch(jf, 1, 1, 16);
    }
  }
}

// Round 11
// 3055.137 us; speedup vs baseline: 2.7200x; 2.0619x over previous
//
#include <hip/hip_runtime.h>
#include <hip/hip_bf16.h>

typedef __hip_bfloat16 bf16;
typedef __attribute__((ext_vector_type(8))) short short8;
typedef __attribute__((ext_vector_type(4))) float f32x4;

#define MFMA(a, b, c) __builtin_amdgcn_mfma_f32_16x16x32_bf16(a, b, c, 0, 0, 0)

__device__ __forceinline__ float to_f(float x) { return x; }
__device__ __forceinline__ float to_f(bf16 x) { return __bfloat162float(x); }
__device__ __forceinline__ float b2f(short s) {
  bf16 h;
  *reinterpret_cast<short*>(&h) = s;
  return __bfloat162float(h);
}
__device__ __forceinline__ short f2b(float f) {
  bf16 h = __float2bfloat16(f);
  return *reinterpret_cast<short*>(&h);
}
__device__ __forceinline__ float ldp(const void* p, size_t i, bool f32) {
  return f32 ? ((const float*)p)[i] : to_f(((const bf16*)p)[i]);
}
__device__ __forceinline__ float fsig(float x) {
  return __builtin_amdgcn_rcpf(1.f + __expf(-x));
}
__device__ __forceinline__ float ftanh(float x) {
  float t = __expf(-2.f * fabsf(x));
  float r = (1.f - t) * __builtin_amdgcn_rcpf(1.f + t);
  return x < 0.f ? -r : r;
}

// dtype probe: f32 data read as u16 pairs shows implausible bf16 exponents.
__global__ void detect_kernel(const void* __restrict__ probe,
                              unsigned* __restrict__ flag) {
  __shared__ int sbad;
  if (threadIdx.x == 0) sbad = 0;
  __syncthreads();
  const unsigned short* u = (const unsigned short*)probe;
  int bad = 0;
  for (int i = threadIdx.x; i < 2048; i += 256) {
    unsigned short w = u[i];
    unsigned e = (w >> 7) & 0xFFu;
    bool plaus = (w == 0) || (w == 0x8000u) || (e >= 0x60u && e <= 0x7Eu);
    if (!plaus) bad++;
  }
  atomicAdd(&sbad, bad);
  __syncthreads();
  if (threadIdx.x == 0) *flag = (sbad > 100) ? 1u : 0u;
}

// ---- weight prep: params (f32|bf16) -> bf16 ws; optional transpose; ----
// ---- src row stride (sstride) for column slicing. ----
#define MAXSEG 28
struct PrepArgs {
  int nseg;
  const void* src[MAXSEG];
  long long soff[MAXSEG];
  short* dst[MAXSEG];
  int scols[MAXSEG];
  int sstride[MAXSEG];
  int dstride[MAXSEG];
  int transp[MAXSEG];
  long long prefix[MAXSEG + 1];
};
__global__ void prep_kernel(PrepArgs a, const unsigned* __restrict__ dflag) {
  const bool isf32 = (*dflag != 0u);
  long long i = (long long)blockIdx.x * 256 + threadIdx.x;
  if (i >= a.prefix[a.nseg]) return;
  int s = 0;
  while (i >= a.prefix[s + 1]) s++;
  long long loc = i - a.prefix[s];
  long long r = loc / a.scols[s], c = loc % a.scols[s];
  float v = ldp(a.src[s], (size_t)(a.soff[s] + r * a.sstride[s] + c), isf32);
  long long idx =
      a.transp[s] ? (c * a.dstride[s] + r) : (r * a.dstride[s] + c);
  a.dst[s][idx] = f2b(v);
}

// ---- multi-job MFMA GEMM, 128x128 tile (round-8 proven version) ----
struct GJob {
  const bf16* A;
  const int* rowidx;
  const short* WT;
  const bf16* bias;
  float* Cf;
  bf16* Ch;
  int lda, wst, K, M, N, flags;  // flags: 1=gather, 4=tanh
};
struct GJobs {
  GJob j[4];
};

__global__ __launch_bounds__(256) void mj_gemm(GJobs args) {
  GJob jb = args.j[blockIdx.z];
  const int n0 = blockIdx.x * 128, m0 = blockIdx.y * 128;
  if (n0 >= jb.N || m0 >= jb.M) return;
  __shared__ short As[128][40];
  __shared__ short Bs[128][40];
  __shared__ int rows[128];
  const int tid = threadIdx.x, lane = tid & 63, wave = tid >> 6;
  const int srow = tid >> 1, skoff = (tid & 1) * 16;
  const int wr = (wave >> 1) * 64, wc = (wave & 1) * 64;
  if (jb.flags & 1) {
    if (tid < 128) rows[tid] = jb.rowidx[m0 + tid];
    __syncthreads();
  }
  const long long arow =
      (jb.flags & 1) ? (long long)rows[srow] : (long long)(m0 + srow);
  const short* abase = (const short*)jb.A + arow * jb.lda + skoff;
  const short* bbase = jb.WT + (long long)(n0 + srow) * jb.wst + skoff;
  f32x4 acc[4][4];
#pragma unroll
  for (int i = 0; i < 4; i++)
#pragma unroll
    for (int j = 0; j < 4; j++) acc[i][j] = 0.f;
  const int K = jb.K;
  short8 a0 = *(const short8*)(abase);
  short8 a1 = *(const short8*)(abase + 8);
  short8 b0 = *(const short8*)(bbase);
  short8 b1 = *(const short8*)(bbase + 8);
  for (int k0 = 0; k0 < K; k0 += 32) {
    __syncthreads();
    *(short8*)&As[srow][skoff] = a0;
    *(short8*)&As[srow][skoff + 8] = a1;
    *(short8*)&Bs[srow][skoff] = b0;
    *(short8*)&Bs[srow][skoff + 8] = b1;
    __syncthreads();
    int kn = (k0 + 32 < K) ? k0 + 32 : k0;
    a0 = *(const short8*)(abase + kn);
    a1 = *(const short8*)(abase + kn + 8);
    b0 = *(const short8*)(bbase + kn);
    b1 = *(const short8*)(bbase + kn + 8);
    short8 af[4], bfr[4];
#pragma unroll
    for (int i = 0; i < 4; i++)
      af[i] = *(short8*)&As[wr + i * 16 + (lane & 15)][(lane >> 4) * 8];
#pragma unroll
    for (int j = 0; j < 4; j++)
      bfr[j] = *(short8*)&Bs[wc + j * 16 + (lane & 15)][(lane >> 4) * 8];
#pragma unroll
    for (int i = 0; i < 4; i++)
#pragma unroll
      for (int j = 0; j < 4; j++)
        acc[i][j] = MFMA(af[i], bfr[j], acc[i][j]);
  }
  const int N = jb.N;
#pragma unroll
  for (int j = 0; j < 4; j++) {
    int col = n0 + wc + j * 16 + (lane & 15);
    float bv = jb.bias ? to_f(jb.bias[col]) : 0.f;
#pragma unroll
    for (int i = 0; i < 4; i++) {
#pragma unroll
      for (int r = 0; r < 4; r++) {
        int row = m0 + wr + i * 16 + (lane >> 4) * 4 + r;
        float v = acc[i][j][r] + bv;
        if (jb.flags & 4) v = ftanh(v);
        if (jb.Cf) jb.Cf[(long long)row * N + col] = v;
        if (jb.Ch) jb.Ch[(long long)row * N + col] = __float2bfloat16(v);
      }
    }
  }
}

// ---- persistent encoder (round-9 proven): block = (32 rows, dir); 24 steps.
__global__ __launch_bounds__(256, 1) void enc_persist(
    const bf16* __restrict__ embE, const int* __restrict__ src,
    const short* __restrict__ WsF, const short* __restrict__ WsB,
    const short* __restrict__ WhnF, const short* __restrict__ WhnB,
    const bf16* __restrict__ BihF, const bf16* __restrict__ BhhF,
    const bf16* __restrict__ BihB, const bf16* __restrict__ BhhB,
    bf16* __restrict__ bse, bf16* __restrict__ hbf) {
  const int dir = blockIdx.y;
  const int b0 = blockIdx.x * 32;
  const short* Ws = dir ? WsB : WsF;
  const short* Whn = dir ? WhnB : WhnF;
  const bf16* Bih = dir ? BihB : BihF;
  const bf16* Bhh = dir ? BhhB : BhhF;
  __shared__ short xh[32][584];  // x 0:320 | h 320:576 | pad
  __shared__ int idx[32];
  const int tid = threadIdx.x, lane = tid & 63, w = tid >> 6;
  const int l15 = lane & 15, q8 = (lane >> 4) * 8, qr = (lane >> 4) * 4;

  float hreg[2][4][4];
#pragma unroll
  for (int m = 0; m < 2; m++)
#pragma unroll
    for (int j = 0; j < 4; j++)
#pragma unroll
      for (int r = 0; r < 4; r++) hreg[m][j][r] = 0.f;
  for (int i = tid; i < 32 * 264; i += 256) xh[i / 264][320 + i % 264] = 0;
  float b_r[4], b_z[4], b_in[4], b_hn[4];
#pragma unroll
  for (int j = 0; j < 4; j++) {
    int c = w * 64 + j * 16 + l15;
    b_r[j] = to_f(Bih[c]) + to_f(Bhh[c]);
    b_z[j] = to_f(Bih[256 + c]) + to_f(Bhh[256 + c]);
    b_in[j] = to_f(Bih[512 + c]);
    b_hn[j] = to_f(Bhh[512 + c]);
  }
  __syncthreads();

  for (int s = 0; s < 24; s++) {
    const int pos = dir ? 23 - s : s;
    if (tid < 32) idx[tid] = src[pos * 2048 + b0 + tid];
    __syncthreads();
    {
      int r = tid >> 3, o = (tid & 7) * 40;
      const short* sp = (const short*)embE + (long long)idx[r] * 320 + o;
      short* dp = &xh[r][o];
#pragma unroll
      for (int u = 0; u < 5; u++)
        *(short8*)(dp + u * 8) = *(const short8*)(sp + u * 8);
    }
    __syncthreads();
    f32x4 accS[24];
    f32x4 accN[8];
#pragma unroll
    for (int i = 0; i < 24; i++) accS[i] = 0.f;
#pragma unroll
    for (int i = 0; i < 8; i++) accN[i] = 0.f;
    {
      const short* bp[12];
#pragma unroll
      for (int g = 0; g < 3; g++)
#pragma unroll
        for (int j = 0; j < 4; j++)
          bp[g * 4 + j] =
              Ws + (long long)(g * 256 + w * 64 + j * 16 + l15) * 576 + q8;
      short8 bb0[12], bb1[12];
#pragma unroll
      for (int i = 0; i < 12; i++) bb0[i] = *(const short8*)bp[i];
      for (int kk = 0; kk < 18; kk += 2) {
        int k1 = (kk + 1) * 32;
#pragma unroll
        for (int i = 0; i < 12; i++) bb1[i] = *(const short8*)(bp[i] + k1);
        {
          short8 a0 = *(short8*)&xh[l15][kk * 32 + q8];
          short8 a1 = *(short8*)&xh[16 + l15][kk * 32 + q8];
#pragma unroll
          for (int i = 0; i < 12; i++) {
            accS[i] = MFMA(a0, bb0[i], accS[i]);
            accS[12 + i] = MFMA(a1, bb0[i], accS[12 + i]);
          }
        }
        if (kk + 2 < 18) {
          int k2 = (kk + 2) * 32;
#pragma unroll
          for (int i = 0; i < 12; i++) bb0[i] = *(const short8*)(bp[i] + k2);
        }
        {
          short8 a0 = *(short8*)&xh[l15][k1 + q8];
          short8 a1 = *(short8*)&xh[16 + l15][k1 + q8];
#pragma unroll
          for (int i = 0; i < 12; i++) {
            accS[i] = MFMA(a0, bb1[i], accS[i]);
            accS[12 + i] = MFMA(a1, bb1[i], accS[12 + i]);
          }
        }
      }
      const short* np = Whn + (long long)(w * 64 + l15) * 256 + q8;
      for (int k0 = 0; k0 < 256; k0 += 32) {
        short8 a0 = *(short8*)&xh[l15][320 + k0 + q8];
        short8 a1 = *(short8*)&xh[16 + l15][320 + k0 + q8];
#pragma unroll
        for (int j = 0; j < 4; j++) {
          short8 b = *(const short8*)(np + (long long)j * 16 * 256 + k0);
          accN[j] = MFMA(a0, b, accN[j]);
          accN[4 + j] = MFMA(a1, b, accN[4 + j]);
        }
      }
    }
    __syncthreads();
#pragma unroll
    for (int j = 0; j < 4; j++) {
      int c = w * 64 + j * 16 + l15;
#pragma unroll
      for (int m = 0; m < 2; m++) {
#pragma unroll
        for (int r = 0; r < 4; r++) {
          int row = m * 16 + qr + r;
          float Sr = accS[m * 12 + j][r];
          float Sz = accS[m * 12 + 4 + j][r];
          float Sn = accS[m * 12 + 8 + j][r];
          float hnr = accN[m * 4 + j][r];
          float rg = fsig(Sr + b_r[j]);
          float zg = fsig(Sz + b_z[j]);
          float nn = ftanh(Sn - hnr + b_in[j] + rg * (hnr + b_hn[j]));
          float o = (1.f - zg) * nn + zg * hreg[m][j][r];
          hreg[m][j][r] = o;
          xh[row][320 + c] = f2b(o);
          bse[((long long)(b0 + row) * 24 + pos) * 512 + dir * 256 + c] =
              __float2bfloat16(o);
        }
      }
    }
    __syncthreads();
  }
#pragma unroll
  for (int j = 0; j < 4; j++) {
    int c = w * 64 + j * 16 + l15;
#pragma unroll
    for (int m = 0; m < 2; m++)
#pragma unroll
      for (int r = 0; r < 4; r++)
        hbf[(long long)(b0 + m * 16 + qr + r) * 512 + dir * 256 + c] =
            __float2bfloat16(hreg[m][j][r]);
  }
}

// decoder GRU cell (round-8): gi (B,768), ghw (B,1024; first 768 = gh).
__global__ __launch_bounds__(256) void dec_cell(
    const bf16* __restrict__ gi, const bf16* __restrict__ ghw,
    float* __restrict__ h_d, bf16* __restrict__ hdbf, bf16* __restrict__ xgc) {
  int b = blockIdx.x, i = threadIdx.x;
  const bf16* gib = gi + (long long)b * 768;
  const bf16* ghb = ghw + (long long)b * 1024;
  float ir = to_f(gib[i]), iz = to_f(gib[256 + i]), in_ = to_f(gib[512 + i]);
  float hr = to_f(ghb[i]), hz = to_f(ghb[256 + i]), hn = to_f(ghb[512 + i]);
  float hv = h_d[(long long)b * 256 + i];
  float r = 1.f / (1.f + expf(-(ir + hr)));
  float z = 1.f / (1.f + expf(-(iz + hz)));
  float n = tanhf(in_ + r * hn);
  float o = (1.f - z) * n + z * hv;
  h_d[(long long)b * 256 + i] = o;
  hdbf[(long long)b * 256 + i] = __float2bfloat16(o);
  xgc[(long long)b * 1088 + 812 + i] = __float2bfloat16(o);
}

// attention + decoder embedding (round-8). hWh = ghw[:,768:1024].
__global__ __launch_bounds__(256) void attn_kernel(
    const bf16* __restrict__ ghw, const bf16* __restrict__ proj,
    const bf16* __restrict__ bse, const void* __restrict__ v,
    const int* __restrict__ trg_t, const bf16* __restrict__ embD,
    bf16* __restrict__ xgc, const unsigned* __restrict__ dflag) {
  const bool isf32 = (*dflag != 0u);
  int b = blockIdx.x, tid = threadIdx.x;
  int wave = tid >> 6, lane = tid & 63;
  __shared__ float partial[24][4];
  __shared__ float aw[24];
  float vh = to_f(ghw[(long long)b * 1024 + 768 + tid]);
  float vv = ldp(v, tid, isf32);
  const bf16* pb = proj + (long long)b * 24 * 256;
#pragma unroll 4
  for (int s = 0; s < 24; s++) {
    float e = tanhf(vh + __bfloat162float(pb[s * 256 + tid]));
    float t = vv * e;
#pragma unroll
    for (int off = 32; off > 0; off >>= 1) t += __shfl_down(t, off, 64);
    if (lane == 0) partial[s][wave] = t;
  }
  __syncthreads();
  if (tid == 0) {
    float sc[24];
    float mx = -1e30f;
    for (int s = 0; s < 24; s++) {
      float xv = partial[s][0] + partial[s][1] + partial[s][2] + partial[s][3];
      sc[s] = xv;
      mx = fmaxf(mx, xv);
    }
    float sum = 0.f;
    for (int s = 0; s < 24; s++) {
      sc[s] = expf(sc[s] - mx);
      sum += sc[s];
    }
    float inv = 1.f / sum;
    for (int s = 0; s < 24; s++) aw[s] = sc[s] * inv;
  }
  __syncthreads();
  const bf16* eb = bse + (long long)b * 24 * 512;
  float w0 = 0.f, w1 = 0.f;
#pragma unroll 4
  for (int s = 0; s < 24; s++) {
    float a = aw[s];
    w0 += a * __bfloat162float(eb[s * 512 + tid]);
    w1 += a * __bfloat162float(eb[s * 512 + 256 + tid]);
  }
  bf16* xb = xgc + (long long)b * 1088;
  xb[300 + tid] = __float2bfloat16(w0);
  xb[556 + tid] = __float2bfloat16(w1);
  long long row = trg_t[b];
  for (int e = tid; e < 300; e += 256) xb[e] = embD[row * 320 + e];
}

__global__ void sentinel_kernel(float* out, int n) {
  int i = blockIdx.x * 256 + threadIdx.x;
  if (i < n) out[i] = 123.0f;
}

extern "C" void kernel_launch(void* const* d_in, const int* in_sizes, int n_in,
                              void* d_out, int out_size, void* d_ws,
                              size_t ws_size, hipStream_t stream) {
  const int B = 2048, T = 25, VOUT = 128;
  const int* src = (const int*)d_in[0];
  const int* trg = (const int*)d_in[1];
  const void* enc_emb = d_in[2];
  const void* enc_Wih_f = d_in[3];
  const void* enc_Whh_f = d_in[4];
  const void* enc_bih_f = d_in[5];
  const void* enc_bhh_f = d_in[6];
  const void* enc_Wih_b = d_in[7];
  const void* enc_Whh_b = d_in[8];
  const void* enc_bih_b = d_in[9];
  const void* enc_bhh_b = d_in[10];
  const void* enc_fcW = d_in[11];
  const void* enc_fcb = d_in[12];
  const void* attn_Wh = d_in[13];
  const void* attn_We = d_in[14];
  const void* attn_b = d_in[15];
  const void* attn_v = d_in[16];
  const void* dec_emb = d_in[17];
  const void* dec_Wih = d_in[18];
  const void* dec_Whh = d_in[19];
  const void* dec_bih = d_in[20];
  const void* dec_bhh = d_in[21];
  const void* fcW = d_in[22];
  const void* fcb = d_in[23];
  float* out = (float*)d_out;

  size_t need = 0;
  auto place = [&](size_t bytes) {
    size_t off = need;
    need += (bytes + 255) & ~(size_t)255;
    return off;
  };
  size_t o_flag = place(256);
  size_t o_w0 = need;
  size_t oEmbE = place(64 * 320 * 2);
  size_t oEmbD = place(128 * 320 * 2);
  size_t oWsF = place(768 * 576 * 2);
  size_t oWsB = place(768 * 576 * 2);
  size_t oWhnF = place(256 * 256 * 2);
  size_t oWhnB = place(256 * 256 * 2);
  size_t oWT5 = place(256 * 512 * 2);
  size_t oWT6 = place(256 * 512 * 2);
  size_t oWcT = place(1024 * 256 * 2);
  size_t oW7T = place(768 * 832 * 2);
  size_t oW8T = place(128 * 1088 * 2);
  size_t oBihF = place(768 * 2), oBhhF = place(768 * 2);
  size_t oBihB = place(768 * 2), oBhhB = place(768 * 2);
  size_t oB5 = place(256 * 2), oB6 = place(256 * 2);
  size_t oB7 = place(768 * 2), oBc = place(1024 * 2), oB8 = place(128 * 2);
  size_t o_w1 = need;
  size_t o_bse = place((size_t)B * 24 * 512 * 2);
  size_t o_proj = place((size_t)B * 24 * 256 * 2);
  size_t o_hbf = place((size_t)B * 512 * 2);
  size_t o_hd = place((size_t)B * 256 * 4);
  size_t o_hdbf = place((size_t)B * 256 * 2);
  size_t o_gi = place((size_t)B * 768 * 2);
  size_t o_ghw = place((size_t)B * 1024 * 2);
  size_t o_xgc = place((size_t)B * 1088 * 2);

  if (ws_size < need) {
    sentinel_kernel<<<(out_size + 255) / 256, 256, 0, stream>>>(out, out_size);
    return;
  }
  char* base = (char*)d_ws;
  unsigned* dflag = (unsigned*)(base + o_flag);
  bf16* embE = (bf16*)(base + oEmbE);
  bf16* embD = (bf16*)(base + oEmbD);
  short* WsF = (short*)(base + oWsF);
  short* WsB = (short*)(base + oWsB);
  short* WhnF = (short*)(base + oWhnF);
  short* WhnB = (short*)(base + oWhnB);
  short* WT5 = (short*)(base + oWT5);
  short* WT6 = (short*)(base + oWT6);
  short* WcT = (short*)(base + oWcT);
  short* W7T = (short*)(base + oW7T);
  short* W8T = (short*)(base + oW8T);
  bf16 *BihF = (bf16*)(base + oBihF), *BhhF = (bf16*)(base + oBhhF);
  bf16 *BihB = (bf16*)(base + oBihB), *BhhB = (bf16*)(base + oBhhB);
  bf16 *B5 = (bf16*)(base + oB5), *B6 = (bf16*)(base + oB6);
  bf16 *B7 = (bf16*)(base + oB7), *Bc = (bf16*)(base + oBc);
  bf16* B8 = (bf16*)(base + oB8);
  bf16* bse = (bf16*)(base + o_bse);
  bf16* proj = (bf16*)(base + o_proj);
  bf16* hbf = (bf16*)(base + o_hbf);
  float* h_d = (float*)(base + o_hd);
  bf16* hdbf = (bf16*)(base + o_hdbf);
  bf16* gi = (bf16*)(base + o_gi);
  bf16* ghw = (bf16*)(base + o_ghw);
  bf16* xgc = (bf16*)(base + o_xgc);

  detect_kernel<<<1, 256, 0, stream>>>(enc_emb, dflag);
  (void)hipMemsetAsync(base + o_w0, 0, o_w1 - o_w0, stream);

  PrepArgs pa;
  int ns = 0;
  long long tot = 0;
  auto seg = [&](const void* s, long long soff, short* dst, int scols,
                 int sstride, int dstride, int transp, long long count) {
    pa.src[ns] = s;
    pa.soff[ns] = soff;
    pa.dst[ns] = dst;
    pa.scols[ns] = scols;
    pa.sstride[ns] = sstride;
    pa.dstride[ns] = dstride;
    pa.transp[ns] = transp;
    pa.prefix[ns] = tot;
    tot += count;
    ns++;
  };
  seg(enc_emb, 0, (short*)embE, 300, 300, 320, 0, 64 * 300);
  seg(dec_emb, 0, (short*)embD, 300, 300, 320, 0, 128 * 300);
  seg(enc_Wih_f, 0, WsF, 768, 768, 576, 1, 300 * 768);
  seg(enc_Whh_f, 0, WsF + 320, 768, 768, 576, 1, 256 * 768);
  seg(enc_Wih_b, 0, WsB, 768, 768, 576, 1, 300 * 768);
  seg(enc_Whh_b, 0, WsB + 320, 768, 768, 576, 1, 256 * 768);
  seg(enc_Whh_f, 512, WhnF, 256, 768, 256, 1, 256 * 256);
  seg(enc_Whh_b, 512, WhnB, 256, 768, 256, 1, 256 * 256);
  seg(enc_fcW, 0, WT5, 256, 256, 512, 1, 512 * 256);
  seg(attn_We, 0, WT6, 256, 256, 512, 1, 512 * 256);
  seg(dec_Whh, 0, WcT, 768, 768, 256, 1, 256 * 768);
  seg(attn_Wh, 0, WcT + 768 * 256, 256, 256, 256, 1, 256 * 256);
  seg(dec_Wih, 0, W7T, 768, 768, 832, 1, 812 * 768);
  // fcW^T k-permuted to xgc = [emb 0:300 | wtd 300:812 | hn 812:1068]
  seg(fcW, (long long)768 * 128, W8T, 128, 128, 1088, 1, 300 * 128);
  seg(fcW, (long long)256 * 128, W8T + 300, 128, 128, 1088, 1, 512 * 128);
  seg(fcW, 0, W8T + 812, 128, 128, 1088, 1, 256 * 128);
  seg(enc_bih_f, 0, (short*)BihF, 768, 768, 768, 0, 768);
  seg(enc_bhh_f, 0, (short*)BhhF, 768, 768, 768, 0, 768);
  seg(enc_bih_b, 0, (short*)BihB, 768, 768, 768, 0, 768);
  seg(enc_bhh_b, 0, (short*)BhhB, 768, 768, 768, 0, 768);
  seg(enc_fcb, 0, (short*)B5, 256, 256, 256, 0, 256);
  seg(attn_b, 0, (short*)B6, 256, 256, 256, 0, 256);
  seg(dec_bih, 0, (short*)B7, 768, 768, 768, 0, 768);
  seg(dec_bhh, 0, (short*)Bc, 768, 768, 768, 0, 768);  // Bc[768:1024]=0
  seg(fcb, 0, (short*)B8, 128, 128, 128, 0, 128);
  pa.prefix[ns] = tot;
  pa.nseg = ns;
  prep_kernel<<<(int)((tot + 255) / 256), 256, 0, stream>>>(pa, dflag);

  (void)hipMemsetAsync(out, 0, (size_t)B * VOUT * 4, stream);  // outputs[0]=0

  // ---- encoder: single persistent kernel ----
  enc_persist<<<dim3(64, 2), 256, 0, stream>>>(embE, src, WsF, WsB, WhnF,
                                               WhnB, BihF, BhhF, BihB, BhhB,
                                               bse, hbf);
  // hidden = tanh([h_f,h_b]@enc_fcW+b) -> h_d + hdbf; proj = bse@attn_We+b
  {
    GJobs a{};
    a.j[0] = {hbf, nullptr, WT5, B5, h_d, hdbf, 512, 512, 512, B, 256, 4};
    a.j[1] = {bse, nullptr, WT6, B6, nullptr, proj, 512, 512, 512, B * 24, 256,
              0};
    mj_gemm<<<dim3(2, 384, 2), 256, 0, stream>>>(a);
  }

  // ---- decoder (round-8 proven structure) ----
  auto wc_job = [&]() -> GJob {
    return {hdbf, nullptr, WcT, Bc, nullptr, ghw, 256, 256, 256, B, 1024, 0};
  };
  {
    GJobs a{};
    a.j[0] = wc_job();
    mj_gemm<<<dim3(8, 16, 1), 256, 0, stream>>>(a);
  }
  for (int t = 0; t < T - 1; t++) {
    attn_kernel<<<B, 256, 0, stream>>>(ghw, proj, bse, attn_v,
                                       trg + (size_t)t * B, embD, xgc, dflag);
    {
      GJobs a{};
      a.j[0] = {xgc, nullptr, W7T, B7, nullptr, gi, 1088, 832, 832, B, 768, 0};
      mj_gemm<<<dim3(6, 16, 1), 256, 0, stream>>>(a);
    }
    dec_cell<<<B, 256, 0, stream>>>(gi, ghw, h_d, hdbf, xgc);
    {
      GJobs a{};
      a.j[0] = {xgc, nullptr, W8T, B8, out + (size_t)(t + 1) * B * VOUT,
                nullptr, 1088, 1088, 1088, B, 128, 0};
      if (t < T - 2) {
        a.j[1] = wc_job();
        mj_gemm<<<dim3(8, 16, 2), 256, 0, stream>>>(a);
      } else {
        mj_gemm<<<dim3(1, 16, 1), 256, 0, stream>>>(a);
      }
    }
  }
}